// Round 1
// baseline (1320.398 us; speedup 1.0000x reference)
//
#include <hip/hip_runtime.h>
#include <math.h>

#define Vv 256
#define Ee 64
#define Hh 128
#define Nn 16384
#define Ll 24
#define G4 512      // 4*H
#define KT 192      // E + H
#define WB 32       // words per task
#define NTHR 256
#define PADW 36     // padded word stride (36*4B = 144B, 16B-aligned rows)
#define NGRP (Nn / WB)      // 512 groups
#define NTASK (NGRP * 2)    // 1024 tasks (group x dir)
#define NBLK (NTASK / 2)    // 512 blocks, snake-paired

__device__ __forceinline__ float sigm(float x) { return 1.0f / (1.0f + __expf(-x)); }
__device__ __forceinline__ float tanh_fast(float x) {
  // tanh(x) = 2*sigmoid(2x) - 1 ; abs err ~1e-7, fine vs 2.77e-3 threshold
  return fmaf(2.0f, 1.0f / (1.0f + __expf(-2.0f * x)), -1.0f);
}

// ---- prep: transpose weights to WT[d][k][j] (k = 0..63 -> Wih^T, 64..191 -> Whh^T), bias sum
__global__ void prep_wt_kernel(const float* __restrict__ Wih_f, const float* __restrict__ Whh_f,
                               const float* __restrict__ bih_f, const float* __restrict__ bhh_f,
                               const float* __restrict__ Wih_b, const float* __restrict__ Whh_b,
                               const float* __restrict__ bih_b, const float* __restrict__ bhh_b,
                               float* __restrict__ WT, float* __restrict__ bsum) {
  int i = blockIdx.x * blockDim.x + threadIdx.x;
  if (i < 2 * KT * G4) {
    int j = i & (G4 - 1);
    int k = (i >> 9) % KT;
    int d = i / (KT * G4);
    const float* Wih = d ? Wih_b : Wih_f;
    const float* Whh = d ? Whh_b : Whh_f;
    WT[i] = (k < Ee) ? Wih[j * Ee + k] : Whh[j * Hh + (k - Ee)];
  }
  if (i < 2 * G4) {
    int d = i >> 9, j = i & (G4 - 1);
    bsum[i] = d ? (bih_b[j] + bhh_b[j]) : (bih_f[j] + bhh_f[j]);
  }
}

// ---- counting sort of words by length (buckets 0..24) so blocks get uniform lengths
__global__ void zero_cnt_kernel(int* cnt) { if (threadIdx.x < 64) cnt[threadIdx.x] = 0; }
__global__ void hist_kernel(const int* __restrict__ lens, int* __restrict__ cnt) {
  int i = blockIdx.x * blockDim.x + threadIdx.x;
  if (i < Nn) atomicAdd(&cnt[lens[i]], 1);
}
__global__ void prefix_kernel(const int* __restrict__ cnt, int* __restrict__ cur) {
  if (threadIdx.x == 0) {
    int s = 0;
    for (int b = 0; b <= Ll; b++) { cur[b] = s; s += cnt[b]; }
  }
}
__global__ void scatter_kernel(const int* __restrict__ lens, int* __restrict__ cur,
                               int* __restrict__ order) {
  int i = blockIdx.x * blockDim.x + threadIdx.x;
  if (i < Nn) { int p = atomicAdd(&cur[lens[i]], 1); order[p] = i; }
}

// ---- main: one task = (group of 32 length-sorted words, direction). Each block
// snake-processes tasks {b, 1023-b} for load balance. Thread tile: 8 words x 8 gate rows,
// rows {2b,2b+1}+{0,128,256,384} so each thread owns both units' full i/f/g/o set.
__global__ __launch_bounds__(NTHR, 2) void bilstm_main(
    const int* __restrict__ cidx, const int* __restrict__ lens,
    const float* __restrict__ emb, const float* __restrict__ WT,
    const float* __restrict__ bsum, const int* __restrict__ order,
    float* __restrict__ out) {
  __shared__ float xh[KT][PADW];   // rows 0..63: x_t, rows 64..191: h (unit-major)
  __shared__ int idx_s[WB][Ll];
  __shared__ int wid_s[WB];
  __shared__ int len_s[WB];
  __shared__ int s_max;

  const int tid = threadIdx.x;
  const int a = tid >> 6;   // word group 0..3 (8 words each)
  const int b = tid & 63;   // unit-pair group
  const int j0 = 2 * b;

  for (int ti = 0; ti < 2; ti++) {
    const int tau = ti ? (NTASK - 1 - (int)blockIdx.x) : (int)blockIdx.x;
    const int g = tau >> 1;
    const int d = tau & 1;

    __syncthreads();  // protect LDS reuse across tasks
    if (tid < WB) wid_s[tid] = order[g * WB + tid];
    if (tid == 0) s_max = 0;
    __syncthreads();
    if (tid < WB) { int l = lens[wid_s[tid]]; len_s[tid] = l; atomicMax(&s_max, l); }
    for (int i = tid; i < WB * Ll; i += NTHR) {
      int w = i / Ll, p = i - w * Ll;
      idx_s[w][p] = cidx[wid_s[w] * Ll + p];
    }
    for (int i = tid; i < Hh * WB; i += NTHR)
      xh[Ee + (i >> 5)][i & 31] = 0.0f;
    __syncthreads();

    const int maxlen = s_max;
    const float* WTd = WT + (size_t)d * (KT * G4);
    const float* bd = bsum + d * G4;
    float bias[8] = {bd[j0], bd[j0 + 1], bd[j0 + 128], bd[j0 + 129],
                     bd[j0 + 256], bd[j0 + 257], bd[j0 + 384], bd[j0 + 385]};
    float c0[8], c1[8];
#pragma unroll
    for (int wi = 0; wi < 8; wi++) { c0[wi] = 0.0f; c1[wi] = 0.0f; }

    for (int t = 0; t < maxlen; t++) {
      // stage x_t: 8 floats per thread, coalesced float4 pair from emb table
      {
        int w = tid >> 3, kc = (tid & 7) << 3;
        int lw = len_s[w];
        int pos = d ? (lw - 1 - t) : t;
        pos = pos < 0 ? 0 : (pos > Ll - 1 ? Ll - 1 : pos);  // clamped; masked out anyway
        int ci = idx_s[w][pos];
        const float4* er = (const float4*)(emb + ci * Ee + kc);
        float4 e0 = er[0], e1 = er[1];
        xh[kc + 0][w] = e0.x; xh[kc + 1][w] = e0.y; xh[kc + 2][w] = e0.z; xh[kc + 3][w] = e0.w;
        xh[kc + 4][w] = e1.x; xh[kc + 5][w] = e1.y; xh[kc + 6][w] = e1.z; xh[kc + 7][w] = e1.w;
      }
      __syncthreads();

      float acc[8][8];
#pragma unroll
      for (int wi = 0; wi < 8; wi++)
#pragma unroll
        for (int r = 0; r < 8; r++) acc[wi][r] = bias[r];

      const float* wr = WTd + j0;
#pragma unroll 2
      for (int k = 0; k < KT; k++) {
        const float* xr = &xh[k][a << 3];
        float4 s0 = *(const float4*)xr;          // LDS broadcast (same addr wave-wide)
        float4 s1 = *(const float4*)(xr + 4);
        const float* wk = wr + (size_t)k * G4;
        float2 w0 = *(const float2*)(wk);        // coalesced 512B/wave
        float2 w1 = *(const float2*)(wk + 128);
        float2 w2 = *(const float2*)(wk + 256);
        float2 w3 = *(const float2*)(wk + 384);
        float sv[8] = {s0.x, s0.y, s0.z, s0.w, s1.x, s1.y, s1.z, s1.w};
#pragma unroll
        for (int wi = 0; wi < 8; wi++) {
          float s = sv[wi];
          acc[wi][0] = fmaf(s, w0.x, acc[wi][0]);
          acc[wi][1] = fmaf(s, w0.y, acc[wi][1]);
          acc[wi][2] = fmaf(s, w1.x, acc[wi][2]);
          acc[wi][3] = fmaf(s, w1.y, acc[wi][3]);
          acc[wi][4] = fmaf(s, w2.x, acc[wi][4]);
          acc[wi][5] = fmaf(s, w2.y, acc[wi][5]);
          acc[wi][6] = fmaf(s, w3.x, acc[wi][6]);
          acc[wi][7] = fmaf(s, w3.y, acc[wi][7]);
        }
      }
      __syncthreads();

      // gate update, c-state in registers; h written back to LDS only if step valid
#pragma unroll
      for (int wi = 0; wi < 8; wi++) {
        int w = (a << 3) + wi;
        if (t < len_s[w]) {
          float ii0 = sigm(acc[wi][0]), ii1 = sigm(acc[wi][1]);
          float ff0 = sigm(acc[wi][2]), ff1 = sigm(acc[wi][3]);
          float gg0 = tanh_fast(acc[wi][4]), gg1 = tanh_fast(acc[wi][5]);
          float oo0 = sigm(acc[wi][6]), oo1 = sigm(acc[wi][7]);
          float cn0 = fmaf(ff0, c0[wi], ii0 * gg0);
          float cn1 = fmaf(ff1, c1[wi], ii1 * gg1);
          c0[wi] = cn0; c1[wi] = cn1;
          xh[Ee + j0][w] = oo0 * tanh_fast(cn0);
          xh[Ee + j0 + 1][w] = oo1 * tanh_fast(cn1);
        }
      }
    }
    __syncthreads();
    for (int i = tid; i < WB * Hh; i += NTHR) {
      int w = i >> 7, u = i & 127;
      out[(size_t)wid_s[w] * (2 * Hh) + d * Hh + u] = xh[Ee + u][w];
    }
  }
}

extern "C" void kernel_launch(void* const* d_in, const int* in_sizes, int n_in,
                              void* d_out, int out_size, void* d_ws, size_t ws_size,
                              hipStream_t stream) {
  const int* cidx = (const int*)d_in[0];
  const int* lens = (const int*)d_in[1];
  const float* emb = (const float*)d_in[2];
  const float* Wih_f = (const float*)d_in[3];
  const float* Whh_f = (const float*)d_in[4];
  const float* bih_f = (const float*)d_in[5];
  const float* bhh_f = (const float*)d_in[6];
  const float* Wih_b = (const float*)d_in[7];
  const float* Whh_b = (const float*)d_in[8];
  const float* bih_b = (const float*)d_in[9];
  const float* bhh_b = (const float*)d_in[10];
  float* out = (float*)d_out;

  // ws layout: WT[2][192][512] f32 | bsum[2][512] f32 | order[N] i32 | cnt[32] | cur[32]
  float* WT = (float*)d_ws;
  float* bsum = WT + 2 * KT * G4;
  int* order = (int*)(bsum + 2 * G4);
  int* cnt = order + Nn;
  int* cur = cnt + 32;

  prep_wt_kernel<<<(2 * KT * G4 + 255) / 256, 256, 0, stream>>>(
      Wih_f, Whh_f, bih_f, bhh_f, Wih_b, Whh_b, bih_b, bhh_b, WT, bsum);
  zero_cnt_kernel<<<1, 64, 0, stream>>>(cnt);
  hist_kernel<<<Nn / 256, 256, 0, stream>>>(lens, cnt);
  prefix_kernel<<<1, 1, 0, stream>>>(cnt, cur);
  scatter_kernel<<<Nn / 256, 256, 0, stream>>>(lens, cur, order);
  bilstm_main<<<NBLK, NTHR, 0, stream>>>(cidx, lens, emb, WT, bsum, order, out);
}

// Round 3
// 787.832 us; speedup vs baseline: 1.6760x; 1.6760x over previous
//
#include <hip/hip_runtime.h>
#include <math.h>

#define Vv 256
#define Ee 64
#define Hh 128
#define Nn 16384
#define Ll 24
#define G4 512      // 4*H
#define WB 32       // words per task
#define NTHR 256
#define PADW 36     // padded word stride in LDS rows (36*4B, 16B-aligned)
#define NGRP (Nn / WB)      // 512 groups
#define NTASK (NGRP * 2)    // 1024 tasks (group x dir) = grid

__device__ __forceinline__ float sigm(float x) { return 1.0f / (1.0f + __expf(-x)); }
__device__ __forceinline__ float tanh_fast(float x) {
  return fmaf(2.0f, 1.0f / (1.0f + __expf(-2.0f * x)), -1.0f);
}

// ---- prep: XGp[d][c][b][m] = emb[c]@Wih_d[j] + bih[j]+bhh[j],  j=(m>>1)*128+2b+(m&1)
//            WTp[d][k][b][m] = Whh_d[j][k]
// Packed so each main-loop thread reads its 8 values as two float4s, coalesced.
__global__ void prep_kernel(const float* __restrict__ emb,
                            const float* __restrict__ Wih_f, const float* __restrict__ Whh_f,
                            const float* __restrict__ bih_f, const float* __restrict__ bhh_f,
                            const float* __restrict__ Wih_b, const float* __restrict__ Whh_b,
                            const float* __restrict__ bih_b, const float* __restrict__ bhh_b,
                            float* __restrict__ WTp, float* __restrict__ XGp) {
  int i = blockIdx.x * blockDim.x + threadIdx.x;
  if (i < 2 * Vv * G4) {  // 262144
    int m = i & 7, b = (i >> 3) & 63, c = (i >> 9) & 255, d = i >> 17;
    int j = ((m >> 1) << 7) + 2 * b + (m & 1);
    const float* Wih = d ? Wih_b : Wih_f;
    const float* bih = d ? bih_b : bih_f;
    const float* bhh = d ? bhh_b : bhh_f;
    float acc = bih[j] + bhh[j];
    const float* er = emb + c * Ee;
    const float* wr = Wih + j * Ee;
#pragma unroll 4
    for (int k = 0; k < Ee; k++) acc = fmaf(er[k], wr[k], acc);
    XGp[i] = acc;
  }
  if (i < 2 * Hh * G4) {  // 131072
    int m = i & 7, b = (i >> 3) & 63, k = (i >> 9) & 127, d = i >> 16;
    int j = ((m >> 1) << 7) + 2 * b + (m & 1);
    const float* Whh = d ? Whh_b : Whh_f;
    WTp[i] = Whh[j * Hh + k];
  }
}

// ---- counting sort of words by length so each block's 32 words have ~equal length
__global__ void zero_cnt_kernel(int* cnt) { if (threadIdx.x < 64) cnt[threadIdx.x] = 0; }
__global__ void hist_kernel(const int* __restrict__ lens, int* __restrict__ cnt) {
  int i = blockIdx.x * blockDim.x + threadIdx.x;
  if (i < Nn) atomicAdd(&cnt[lens[i]], 1);
}
__global__ void prefix_kernel(const int* __restrict__ cnt, int* __restrict__ cur) {
  if (threadIdx.x == 0) {
    int s = 0;
    for (int b = 0; b <= Ll; b++) { cur[b] = s; s += cnt[b]; }
  }
}
__global__ void scatter_kernel(const int* __restrict__ lens, int* __restrict__ cur,
                               int* __restrict__ order) {
  int i = blockIdx.x * blockDim.x + threadIdx.x;
  if (i < Nn) { int p = atomicAdd(&cur[lens[i]], 1); order[p] = i; }
}

// ---- main: 1024 blocks, one task (32 sorted words x 1 direction) each, longest first.
// Thread tile: 8 words x 8 gate rows {2b,2b+1}+{0,128,256,384}. Recurrent K=128 only;
// x-contribution comes from the precomputed XGp gather.
__global__ __launch_bounds__(NTHR, 4) void bilstm_main(
    const int* __restrict__ cidx, const int* __restrict__ lens,
    const float* __restrict__ WTp, const float* __restrict__ XGp,
    const int* __restrict__ order, float* __restrict__ out) {
  __shared__ float hb[Hh][PADW];
  __shared__ int idx_s[WB][Ll];
  __shared__ int wid_s[WB];
  __shared__ int len_s[WB];

  const int tid = threadIdx.x;
  const int a8 = (tid >> 6) << 3;  // first word of this thread's 8-word tile
  const int b = tid & 63;
  const int j0 = 2 * b;
  const int task = NTASK - 1 - (int)blockIdx.x;  // longest first
  const int g = task >> 1;
  const int d = task & 1;

  if (tid < WB) {
    int w = order[g * WB + tid];
    wid_s[tid] = w;
    len_s[tid] = lens[w];
  }
  __syncthreads();
  for (int i = tid; i < WB * Ll; i += NTHR) {
    int w = i / Ll, p = i - w * Ll;
    idx_s[w][p] = cidx[(size_t)wid_s[w] * Ll + p];
  }
  for (int i = tid; i < Hh * WB; i += NTHR) hb[i >> 5][i & 31] = 0.0f;
  __syncthreads();

  const int maxlen = len_s[WB - 1];  // sorted ascending -> last word has group max
  const float4* wt4 = (const float4*)(WTp + (size_t)d * (Hh * G4));
  const float* xg = XGp + (size_t)d * (Vv * G4);

  int wlen[8];
#pragma unroll
  for (int wi = 0; wi < 8; wi++) wlen[wi] = len_s[a8 + wi];
  float c0[8], c1[8];
#pragma unroll
  for (int wi = 0; wi < 8; wi++) { c0[wi] = 0.0f; c1[wi] = 0.0f; }

  for (int t = 0; t < maxlen; t++) {
    float acc[8][8];
    // init acc from XGp gather: per word, two coalesced float4s (all lanes same char row)
#pragma unroll
    for (int wi = 0; wi < 8; wi++) {
      int lw = wlen[wi];
      int pos = d ? (lw - 1 - t) : t;
      pos = pos < 0 ? 0 : (pos > Ll - 1 ? Ll - 1 : pos);
      int c = idx_s[a8 + wi][pos];
      const float4* xr = (const float4*)(xg + ((size_t)c << 9)) + (b << 1);
      float4 x0 = xr[0], x1 = xr[1];
      acc[wi][0] = x0.x; acc[wi][1] = x0.y; acc[wi][2] = x0.z; acc[wi][3] = x0.w;
      acc[wi][4] = x1.x; acc[wi][5] = x1.y; acc[wi][6] = x1.z; acc[wi][7] = x1.w;
    }

    if (t > 0) {  // h == 0 at t=0 -> matmul contributes nothing
#pragma unroll 2
      for (int k = 0; k < Hh; k++) {
        float4 s0 = *(const float4*)&hb[k][a8];       // wave-uniform broadcast
        float4 s1 = *(const float4*)&hb[k][a8 + 4];
        float4 u0 = wt4[((size_t)k << 7) + (b << 1)];     // k-stride = 512 floats = 128 float4
        float4 u1 = wt4[((size_t)k << 7) + (b << 1) + 1];
        float sv[8] = {s0.x, s0.y, s0.z, s0.w, s1.x, s1.y, s1.z, s1.w};
        float wv[8] = {u0.x, u0.y, u0.z, u0.w, u1.x, u1.y, u1.z, u1.w};
#pragma unroll
        for (int wi = 0; wi < 8; wi++) {
          float s = sv[wi];
#pragma unroll
          for (int r = 0; r < 8; r++) acc[wi][r] = fmaf(s, wv[r], acc[wi][r]);
        }
      }
    }
    __syncthreads();  // all reads of hb done before writes

#pragma unroll
    for (int wi = 0; wi < 8; wi++) {
      int w = a8 + wi;
      if (t < wlen[wi]) {
        float ii0 = sigm(acc[wi][0]), ii1 = sigm(acc[wi][1]);
        float ff0 = sigm(acc[wi][2]), ff1 = sigm(acc[wi][3]);
        float gg0 = tanh_fast(acc[wi][4]), gg1 = tanh_fast(acc[wi][5]);
        float oo0 = sigm(acc[wi][6]), oo1 = sigm(acc[wi][7]);
        float cn0 = fmaf(ff0, c0[wi], ii0 * gg0);
        float cn1 = fmaf(ff1, c1[wi], ii1 * gg1);
        c0[wi] = cn0; c1[wi] = cn1;
        hb[j0][w] = oo0 * tanh_fast(cn0);
        hb[j0 + 1][w] = oo1 * tanh_fast(cn1);
      }
    }
    __syncthreads();  // writes visible before next step's reads
  }

  for (int i = tid; i < WB * Hh; i += NTHR) {
    int w = i >> 7, u = i & 127;
    out[(size_t)wid_s[w] * (2 * Hh) + d * Hh + u] = hb[u][w];
  }
}

extern "C" void kernel_launch(void* const* d_in, const int* in_sizes, int n_in,
                              void* d_out, int out_size, void* d_ws, size_t ws_size,
                              hipStream_t stream) {
  const int* cidx = (const int*)d_in[0];
  const int* lens = (const int*)d_in[1];
  const float* emb = (const float*)d_in[2];
  const float* Wih_f = (const float*)d_in[3];
  const float* Whh_f = (const float*)d_in[4];
  const float* bih_f = (const float*)d_in[5];
  const float* bhh_f = (const float*)d_in[6];
  const float* Wih_b = (const float*)d_in[7];
  const float* Whh_b = (const float*)d_in[8];
  const float* bih_b = (const float*)d_in[9];
  const float* bhh_b = (const float*)d_in[10];
  float* out = (float*)d_out;

  // ws: WTp[2*128*512] f32 | XGp[2*256*512] f32 | order[N] i32 | cnt[32] | cur[32]
  float* WTp = (float*)d_ws;
  float* XGp = WTp + 2 * Hh * G4;
  int* order = (int*)(XGp + 2 * Vv * G4);
  int* cnt = order + Nn;
  int* cur = cnt + 32;

  prep_kernel<<<(2 * Vv * G4 + NTHR - 1) / NTHR, NTHR, 0, stream>>>(
      emb, Wih_f, Whh_f, bih_f, bhh_f, Wih_b, Whh_b, bih_b, bhh_b, WTp, XGp);
  zero_cnt_kernel<<<1, 64, 0, stream>>>(cnt);
  hist_kernel<<<Nn / NTHR, NTHR, 0, stream>>>(lens, cnt);
  prefix_kernel<<<1, 1, 0, stream>>>(cnt, cur);
  scatter_kernel<<<Nn / NTHR, NTHR, 0, stream>>>(lens, cur, order);
  bilstm_main<<<NTASK, NTHR, 0, stream>>>(cidx, lens, WTp, XGp, order, out);
}

// Round 4
// 297.988 us; speedup vs baseline: 4.4310x; 2.6438x over previous
//
#include <hip/hip_runtime.h>
#include <math.h>

#define Vv 256
#define Ee 64
#define Hh 128
#define Nn 16384
#define Ll 24
#define G4 512      // 4*H
#define WB 32       // words per task
#define NTHR 512    // 8 waves
#define NGRP (Nn / WB)      // 512 groups
#define NTASK (NGRP * 2)    // 1024 tasks (group x dir) = grid

typedef _Float16 half8 __attribute__((ext_vector_type(8)));
typedef float f32x4 __attribute__((ext_vector_type(4)));

__device__ __forceinline__ float sigm(float x) { return 1.0f / (1.0f + __expf(-x)); }
__device__ __forceinline__ float tanh_fast(float x) {
  return fmaf(2.0f, 1.0f / (1.0f + __expf(-2.0f * x)), -1.0f);
}

// ---- prep:
// XG[d][c][j]  (f32): emb[c]@Wih_d[j] + bih[j] + bhh[j], j in PyTorch gate order (i,f,g,o banks of 128)
// BP[d][kt][bank][qg][u][e] (f16): Whh_d[bank*128+u][kt*32+qg*8+e] — B-fragment order for
//   mfma_f32_16x16x32_f16: lane L reads 8 halves at (qg=L>>4, u matched to col=L&15).
__global__ void prep_kernel(const float* __restrict__ emb,
                            const float* __restrict__ Wih_f, const float* __restrict__ Whh_f,
                            const float* __restrict__ bih_f, const float* __restrict__ bhh_f,
                            const float* __restrict__ Wih_b, const float* __restrict__ Whh_b,
                            const float* __restrict__ bih_b, const float* __restrict__ bhh_b,
                            _Float16* __restrict__ BP, float* __restrict__ XG) {
  int i = blockIdx.x * blockDim.x + threadIdx.x;
  if (i < 2 * Vv * G4) {  // 262144
    int j = i & 511, c = (i >> 9) & 255, d = i >> 17;
    const float* Wih = d ? Wih_b : Wih_f;
    const float* bih = d ? bih_b : bih_f;
    const float* bhh = d ? bhh_b : bhh_f;
    float acc = bih[j] + bhh[j];
    const float* er = emb + c * Ee;
    const float* wr = Wih + j * Ee;
#pragma unroll 4
    for (int k = 0; k < Ee; k++) acc = fmaf(er[k], wr[k], acc);
    XG[i] = acc;
  }
  if (i < 2 * 4 * 4 * 4 * 128 * 8) {  // 131072
    int e = i & 7, u = (i >> 3) & 127, g2 = (i >> 10) & 3,
        bank = (i >> 12) & 3, kt = (i >> 14) & 3, d = (i >> 16) & 1;
    int j = bank * 128 + u;
    int k = kt * 32 + g2 * 8 + e;
    const float* Whh = d ? Whh_b : Whh_f;
    BP[i] = (_Float16)Whh[j * Hh + k];
  }
}

// ---- counting sort of words by length so each block's 32 words have ~equal length
__global__ void zero_cnt_kernel(int* cnt) { if (threadIdx.x < 64) cnt[threadIdx.x] = 0; }
__global__ void hist_kernel(const int* __restrict__ lens, int* __restrict__ cnt) {
  int i = blockIdx.x * blockDim.x + threadIdx.x;
  if (i < Nn) atomicAdd(&cnt[lens[i]], 1);
}
__global__ void prefix_kernel(const int* __restrict__ cnt, int* __restrict__ cur) {
  if (threadIdx.x == 0) {
    int s = 0;
    for (int b = 0; b <= Ll; b++) { cur[b] = s; s += cnt[b]; }
  }
}
__global__ void scatter_kernel(const int* __restrict__ lens, int* __restrict__ cur,
                               int* __restrict__ order) {
  int i = blockIdx.x * blockDim.x + threadIdx.x;
  if (i < Nn) { int p = atomicAdd(&cur[lens[i]], 1); order[p] = i; }
}

// ---- main: 1024 tasks (32 sorted words x dir), one 8-wave block each, longest first.
// Wave wv owns units [16wv,16wv+16); Whh lives in VGPRs (Bf[4][4] half8 = 64 VGPR).
// Per step: XG gather -> acc; ds_read h frags; MFMA over 4 K-tiles x 4 gate banks;
// gate nonlinearity with c/h in regs; fp16 h writeback to single-buffered LDS.
__global__ __launch_bounds__(NTHR, 2) void bilstm_main(
    const int* __restrict__ cidx, const int* __restrict__ lens,
    const _Float16* __restrict__ BP, const float* __restrict__ XG,
    const int* __restrict__ order, float* __restrict__ out) {
  __shared__ __align__(16) _Float16 hs[WB][136];  // pad 136: 272B rows, 2-way-bank (free)
  __shared__ int idx_s[WB][Ll];
  __shared__ int wid_s[WB];
  __shared__ int len_s[WB];

  const int tid = threadIdx.x;
  const int lane = tid & 63;
  const int wv = tid >> 6;        // wave 0..7
  const int qg = lane >> 4;       // quarter-group 0..3 (k-octet / row-quad select)
  const int li = lane & 15;       // col within tile
  const int u = (wv << 4) + li;   // this lane's unit 0..127

  const int task = NTASK - 1 - (int)blockIdx.x;  // longest first
  const int g = task >> 1;
  const int d = task & 1;

  if (tid < WB) { int w = order[g * WB + tid]; wid_s[tid] = w; len_s[tid] = lens[w]; }
  __syncthreads();
  for (int i = tid; i < WB * Ll; i += NTHR) {
    int w = i / Ll, p = i - w * Ll;
    idx_s[w][p] = cidx[(size_t)wid_s[w] * Ll + p];
  }
  for (int i = tid; i < WB * 136; i += NTHR) ((_Float16*)hs)[i] = (_Float16)0.0f;
  __syncthreads();

  const int maxlen = len_s[WB - 1];  // ascending sort -> group max

  // Whh fragments -> registers, once per task. Lane reads 16B, quarter-wave coalesced.
  half8 Bf[4][4];
  {
    const _Float16* BPd = BP + (size_t)d * 65536;
#pragma unroll
    for (int kt = 0; kt < 4; kt++)
#pragma unroll
      for (int bank = 0; bank < 4; bank++)
        Bf[kt][bank] = *(const half8*)(BPd + (size_t)((((kt * 4 + bank) * 4 + qg) * 128 + u) << 3));
  }

  const float* xgd = XG + (size_t)d * (Vv * G4);

  int wrd[2][4], wlen[2][4];
#pragma unroll
  for (int mt = 0; mt < 2; mt++)
#pragma unroll
    for (int r = 0; r < 4; r++) {
      int w = mt * 16 + qg * 4 + r;   // C/D row = (lane>>4)*4 + reg
      wrd[mt][r] = w;
      wlen[mt][r] = len_s[w];
    }

  float cst[2][4], hreg[2][4];
#pragma unroll
  for (int mt = 0; mt < 2; mt++)
#pragma unroll
    for (int r = 0; r < 4; r++) { cst[mt][r] = 0.0f; hreg[mt][r] = 0.0f; }

  for (int t = 0; t < maxlen; t++) {
    // acc init = XG gather (32 scalar loads, issued before LDS reads -> latency hidden)
    f32x4 acc[2][4];
    const float* xrow[2][4];
#pragma unroll
    for (int mt = 0; mt < 2; mt++)
#pragma unroll
      for (int r = 0; r < 4; r++) {
        int pos = d ? (wlen[mt][r] - 1 - t) : t;
        pos = pos < 0 ? 0 : (pos > Ll - 1 ? Ll - 1 : pos);
        int c = idx_s[wrd[mt][r]][pos];
        xrow[mt][r] = xgd + ((size_t)c << 9) + u;
      }
#pragma unroll
    for (int mt = 0; mt < 2; mt++)
#pragma unroll
      for (int bank = 0; bank < 4; bank++)
#pragma unroll
        for (int r = 0; r < 4; r++)
          acc[mt][bank][r] = xrow[mt][r][bank << 7];

    if (t > 0) {  // h==0 at t=0: matmul contributes nothing
      // A frags: lane L holds h[word=mt*16+(L&15)][k = kt*32+(L>>4)*8 ..+8]
      half8 a[2][4];
#pragma unroll
      for (int mt = 0; mt < 2; mt++)
#pragma unroll
        for (int kt = 0; kt < 4; kt++)
          a[mt][kt] = *(const half8*)&hs[mt * 16 + li][kt * 32 + qg * 8];
      __syncthreads();  // barrier A: all waves' h reads done before any h write
#pragma unroll
      for (int mt = 0; mt < 2; mt++)
#pragma unroll
        for (int bank = 0; bank < 4; bank++) {
          f32x4 v = acc[mt][bank];
#pragma unroll
          for (int kt = 0; kt < 4; kt++)
            v = __builtin_amdgcn_mfma_f32_16x16x32_f16(a[mt][kt], Bf[kt][bank], v, 0, 0, 0);
          acc[mt][bank] = v;
        }
    }

    // gates: lane has i,f,g,o (banks 0..3) for (word wrd[mt][r], unit u); c,h in regs
#pragma unroll
    for (int mt = 0; mt < 2; mt++)
#pragma unroll
      for (int r = 0; r < 4; r++) {
        float gi = sigm(acc[mt][0][r]);
        float gf = sigm(acc[mt][1][r]);
        float gg = tanh_fast(acc[mt][2][r]);
        float go = sigm(acc[mt][3][r]);
        float cn = fmaf(gf, cst[mt][r], gi * gg);
        float hn = go * tanh_fast(cn);
        if (t < wlen[mt][r]) {  // masked: state persists (hs untouched)
          cst[mt][r] = cn;
          hreg[mt][r] = hn;
          hs[wrd[mt][r]][u] = (_Float16)hn;
        }
      }
    __syncthreads();  // barrier B: h writes visible to next step's reads
  }

  // output from fp32 regs (skips fp16 quantization on the output path)
#pragma unroll
  for (int mt = 0; mt < 2; mt++)
#pragma unroll
    for (int r = 0; r < 4; r++)
      out[(size_t)wid_s[wrd[mt][r]] * (2 * Hh) + d * Hh + u] = hreg[mt][r];
}

extern "C" void kernel_launch(void* const* d_in, const int* in_sizes, int n_in,
                              void* d_out, int out_size, void* d_ws, size_t ws_size,
                              hipStream_t stream) {
  const int* cidx = (const int*)d_in[0];
  const int* lens = (const int*)d_in[1];
  const float* emb = (const float*)d_in[2];
  const float* Wih_f = (const float*)d_in[3];
  const float* Whh_f = (const float*)d_in[4];
  const float* bih_f = (const float*)d_in[5];
  const float* bhh_f = (const float*)d_in[6];
  const float* Wih_b = (const float*)d_in[7];
  const float* Whh_b = (const float*)d_in[8];
  const float* bih_b = (const float*)d_in[9];
  const float* bhh_b = (const float*)d_in[10];
  float* out = (float*)d_out;

  // ws: BP f16 [2*4*4*4*128*8] = 256KB | XG f32 [2*256*512] = 1MB | order[N] | cnt | cur
  char* base = (char*)d_ws;
  _Float16* BP = (_Float16*)base;
  float* XGp = (float*)(base + 262144);
  int* order = (int*)(base + 262144 + 1048576);
  int* cnt = order + Nn;
  int* cur = cnt + 32;

  prep_kernel<<<(2 * Vv * G4 + 255) / 256, 256, 0, stream>>>(
      emb, Wih_f, Whh_f, bih_f, bhh_f, Wih_b, Whh_b, bih_b, bhh_b, BP, XGp);
  zero_cnt_kernel<<<1, 64, 0, stream>>>(cnt);
  hist_kernel<<<Nn / 256, 256, 0, stream>>>(lens, cnt);
  prefix_kernel<<<1, 1, 0, stream>>>(cnt, cur);
  scatter_kernel<<<Nn / 256, 256, 0, stream>>>(lens, cur, order);
  bilstm_main<<<NTASK, NTHR, 0, stream>>>(cidx, lens, BP, XGp, order, out);
}

// Round 5
// 229.289 us; speedup vs baseline: 5.7587x; 1.2996x over previous
//
#include <hip/hip_runtime.h>
#include <math.h>

#define Vv 256
#define Ee 64
#define Hh 128
#define Nn 16384
#define Ll 24
#define G4 512      // 4*H
#define WB 32       // words per task
#define NTHR 512    // 8 waves
#define NGRP (Nn / WB)      // 512 groups
#define NTASK (NGRP * 2)    // 1024 tasks (group x dir) = grid

typedef _Float16 half8 __attribute__((ext_vector_type(8)));
typedef float f32x4 __attribute__((ext_vector_type(4)));

#define KS1 (-1.4426950408889634f)   // -log2(e): i,f,o rows -> A=2^(s)=exp(-y)
#define KS2 (-2.8853900817779268f)   // -2*log2(e): g rows -> C=exp(-2y)
#define KD  (-2.8853900817779268f)   // cn -> sD

// ---- prep (also zeroes cnt):
// XGq[d][c][u][bank] (f32, float4 per (c,u)): (emb[c]@Wih_d[j] + bih[j]+bhh[j]) * scale(bank),
//   j = bank*128+u. scale folds the exp->exp2 conversion into the preactivations.
// BP[d][kt][bank][g2][u][e] (f16): Whh_d[j][k]*scale(bank), k=kt*32+g2*8+e (B-frag order,
//   same packing as round 4 which passed).
__global__ void prep_kernel(const float* __restrict__ emb,
                            const float* __restrict__ Wih_f, const float* __restrict__ Whh_f,
                            const float* __restrict__ bih_f, const float* __restrict__ bhh_f,
                            const float* __restrict__ Wih_b, const float* __restrict__ Whh_b,
                            const float* __restrict__ bih_b, const float* __restrict__ bhh_b,
                            _Float16* __restrict__ BP, float* __restrict__ XGq,
                            int* __restrict__ cnt) {
  int i = blockIdx.x * blockDim.x + threadIdx.x;
  if (i < 64) cnt[i] = 0;
  if (i < 2 * Vv * G4) {  // 262144
    int bank = i & 3, u = (i >> 2) & 127, c = (i >> 9) & 255, d = i >> 17;
    int j = bank * 128 + u;
    const float* Wih = d ? Wih_b : Wih_f;
    const float* bih = d ? bih_b : bih_f;
    const float* bhh = d ? bhh_b : bhh_f;
    float acc = bih[j] + bhh[j];
    const float4* e4 = (const float4*)(emb + c * Ee);
    const float4* w4 = (const float4*)(Wih + j * Ee);
#pragma unroll 4
    for (int k = 0; k < Ee / 4; k++) {
      float4 a = e4[k], b = w4[k];
      acc = fmaf(a.x, b.x, acc); acc = fmaf(a.y, b.y, acc);
      acc = fmaf(a.z, b.z, acc); acc = fmaf(a.w, b.w, acc);
    }
    XGq[i] = acc * ((bank == 2) ? KS2 : KS1);
  }
  if (i < 2 * 4 * 4 * 4 * 128 * 8) {  // 131072
    int e = i & 7, u = (i >> 3) & 127, g2 = (i >> 10) & 3,
        bank = (i >> 12) & 3, kt = (i >> 14) & 3, d = (i >> 16) & 1;
    int j = bank * 128 + u;
    int k = kt * 32 + g2 * 8 + e;
    const float* Whh = d ? Whh_b : Whh_f;
    BP[i] = (_Float16)(Whh[j * Hh + k] * ((bank == 2) ? KS2 : KS1));
  }
}

// ---- counting sort of words by length so each block's 32 words have ~equal length
__global__ void hist_kernel(const int* __restrict__ lens, int* __restrict__ cnt) {
  int i = blockIdx.x * blockDim.x + threadIdx.x;
  if (i < Nn) atomicAdd(&cnt[lens[i]], 1);
}
__global__ void prefix_kernel(const int* __restrict__ cnt, int* __restrict__ cur) {
  if (threadIdx.x == 0) {
    int s = 0;
    for (int b = 0; b <= Ll; b++) { cur[b] = s; s += cnt[b]; }
  }
}
__global__ void scatter_kernel(const int* __restrict__ lens, int* __restrict__ cur,
                               int* __restrict__ order) {
  int i = blockIdx.x * blockDim.x + threadIdx.x;
  if (i < Nn) { int p = atomicAdd(&cur[lens[i]], 1); order[p] = i; }
}

// Gates with shared-rcp algebra. ACC[bank][r] holds exp2-ready preactivations:
// A=2^ACC0=exp(-yi), B=exp(-yf), C=exp(-2yg), E=exp(-yo).
// cn = c/(1+B) + (1-C)/((1+A)(1+C)); h = (1-D)/((1+D)(1+E)), D=exp(-2cn).
#define GATES(ACC, CS, HR, MT, WLEN)                                          \
  _Pragma("unroll") for (int r = 0; r < 4; r++) {                             \
    float Av = exp2f(ACC[0][r]);                                              \
    float Bv = exp2f(ACC[1][r]);                                              \
    float Cv = exp2f(ACC[2][r]);                                              \
    float Ev = exp2f(ACC[3][r]);                                              \
    float aA = 1.0f + Av, aB = 1.0f + Bv, aC = 1.0f + Cv, aE = 1.0f + Ev;     \
    float p13 = aA * aC;                                                      \
    float R1 = __builtin_amdgcn_rcpf(p13 * aB);                               \
    float cn = fmaf(CS[r], p13, (1.0f - Cv) * aB) * R1;                       \
    float Dv = exp2f(cn * KD);                                                \
    float R2 = __builtin_amdgcn_rcpf((1.0f + Dv) * aE);                       \
    float hn = (1.0f - Dv) * R2;                                              \
    if (t < WLEN[r]) {                                                        \
      CS[r] = cn; HR[r] = hn;                                                 \
      hw[(MT)*16 + qg * 4 + r][u] = (_Float16)hn;                             \
    }                                                                         \
  }

#define LOADX(XV, MT, WLEN, TT)                                               \
  _Pragma("unroll") for (int r = 0; r < 4; r++) {                             \
    int pos = d ? (WLEN[r] - 1 - (TT)) : (TT);                                \
    pos = pos < 0 ? 0 : (pos > Ll - 1 ? Ll - 1 : pos);                        \
    int c = idx_s[(MT)*16 + qg * 4 + r][pos];                                 \
    XV[r] = xq[(c << 7) + u];                                                 \
  }

// ---- main: 1024 tasks (32 sorted words x dir), one 8-wave block each, longest first.
// Whh in VGPRs (Bf). Per step: prefetched XGq float4 gather -> acc; ds_read h frags
// (double-buffered LDS, ONE barrier/step); MFMA; shared-rcp gates; f16 h writeback.
__global__ __launch_bounds__(NTHR, 2) void bilstm_main(
    const int* __restrict__ cidx, const int* __restrict__ lens,
    const _Float16* __restrict__ BP, const float* __restrict__ XGq,
    const int* __restrict__ order, float* __restrict__ out) {
  __shared__ __align__(16) _Float16 hs[2][WB][136];  // dbuf; pad 136 -> 2-way bank (free)
  __shared__ int idx_s[WB][Ll];
  __shared__ int wid_s[WB];
  __shared__ int len_s[WB];

  const int tid = threadIdx.x;
  const int lane = tid & 63;
  const int wv = tid >> 6;        // wave 0..7
  const int qg = lane >> 4;       // quarter-group 0..3
  const int li = lane & 15;       // col within tile
  const int u = (wv << 4) + li;   // this lane's unit 0..127

  const int task = NTASK - 1 - (int)blockIdx.x;  // longest first
  const int g = task >> 1;
  const int d = task & 1;

  if (tid < WB) { int w = order[g * WB + tid]; wid_s[tid] = w; len_s[tid] = lens[w]; }
  __syncthreads();
  for (int i = tid; i < WB * Ll; i += NTHR) {
    int w = i / Ll, p = i - w * Ll;
    idx_s[w][p] = cidx[(size_t)wid_s[w] * Ll + p];
  }
  for (int i = tid; i < 2 * WB * 136; i += NTHR) ((_Float16*)hs)[i] = (_Float16)0.0f;
  __syncthreads();

  const int maxlen = len_s[WB - 1];  // ascending sort -> group max

  // Whh fragments -> registers (pre-scaled), once per task.
  half8 Bf[4][4];
  {
    const _Float16* BPd = BP + (size_t)d * 65536;
#pragma unroll
    for (int kt = 0; kt < 4; kt++)
#pragma unroll
      for (int bank = 0; bank < 4; bank++)
        Bf[kt][bank] = *(const half8*)(BPd + (size_t)((((kt * 4 + bank) * 4 + qg) * 128 + u) << 3));
  }

  const f32x4* xq = (const f32x4*)(XGq + (size_t)d * (Vv * G4));

  int wlen0[4], wlen1[4];
#pragma unroll
  for (int r = 0; r < 4; r++) {
    wlen0[r] = len_s[qg * 4 + r];        // C/D row = (lane>>4)*4 + reg
    wlen1[r] = len_s[16 + qg * 4 + r];
  }
  float cst0[4], cst1[4], hreg0[4], hreg1[4];
#pragma unroll
  for (int r = 0; r < 4; r++) { cst0[r] = 0.0f; cst1[r] = 0.0f; hreg0[r] = 0.0f; hreg1[r] = 0.0f; }

  f32x4 x4a[4], x4b[4];
  if (maxlen > 0) { LOADX(x4a, 0, wlen0, 0); LOADX(x4b, 1, wlen1, 0); }

  for (int t = 0; t < maxlen; t++) {
    _Float16 (*hw)[136] = hs[t & 1];                 // write buffer
    const _Float16 (*hr)[136] = hs[(t ^ 1) & 1];     // read buffer = (t-1)&1

    // acc init from prefetched gather (loads issued last iteration)
    f32x4 acc0[4], acc1[4];
#pragma unroll
    for (int bank = 0; bank < 4; bank++)
#pragma unroll
      for (int r = 0; r < 4; r++) {
        acc0[bank][r] = x4a[r][bank];
        acc1[bank][r] = x4b[r][bank];
      }

    if (t > 0) {  // h==0 at t=0: matmul contributes nothing
      half8 a0[4], a1[4];
#pragma unroll
      for (int kt = 0; kt < 4; kt++) {
        a0[kt] = *(const half8*)&hr[li][kt * 32 + qg * 8];
        a1[kt] = *(const half8*)&hr[16 + li][kt * 32 + qg * 8];
      }
#pragma unroll
      for (int bank = 0; bank < 4; bank++) {
        f32x4 v0 = acc0[bank], v1 = acc1[bank];
#pragma unroll
        for (int kt = 0; kt < 4; kt++) {
          v0 = __builtin_amdgcn_mfma_f32_16x16x32_f16(a0[kt], Bf[kt][bank], v0, 0, 0, 0);
          v1 = __builtin_amdgcn_mfma_f32_16x16x32_f16(a1[kt], Bf[kt][bank], v1, 0, 0, 0);
        }
        acc0[bank] = v0; acc1[bank] = v1;
      }
    }

    // prefetch next step's gather; L2 latency hides under the trans-heavy gates.
    if (t + 1 < maxlen) { LOADX(x4a, 0, wlen0, t + 1); LOADX(x4b, 1, wlen1, t + 1); }

    GATES(acc0, cst0, hreg0, 0, wlen0);
    GATES(acc1, cst1, hreg1, 1, wlen1);

    __syncthreads();  // writes to hs[t&1] visible before next step reads it
  }

  // output from fp32 regs
#pragma unroll
  for (int r = 0; r < 4; r++) {
    out[(size_t)wid_s[qg * 4 + r] * (2 * Hh) + d * Hh + u] = hreg0[r];
    out[(size_t)wid_s[16 + qg * 4 + r] * (2 * Hh) + d * Hh + u] = hreg1[r];
  }
}

extern "C" void kernel_launch(void* const* d_in, const int* in_sizes, int n_in,
                              void* d_out, int out_size, void* d_ws, size_t ws_size,
                              hipStream_t stream) {
  const int* cidx = (const int*)d_in[0];
  const int* lens = (const int*)d_in[1];
  const float* emb = (const float*)d_in[2];
  const float* Wih_f = (const float*)d_in[3];
  const float* Whh_f = (const float*)d_in[4];
  const float* bih_f = (const float*)d_in[5];
  const float* bhh_f = (const float*)d_in[6];
  const float* Wih_b = (const float*)d_in[7];
  const float* Whh_b = (const float*)d_in[8];
  const float* bih_b = (const float*)d_in[9];
  const float* bhh_b = (const float*)d_in[10];
  float* out = (float*)d_out;

  // ws: BP f16 [131072] = 256KB | XGq f32 [2*256*512] = 1MB | order[N] | cnt[64] | cur[64]
  char* base = (char*)d_ws;
  _Float16* BP = (_Float16*)base;
  float* XGq = (float*)(base + 262144);
  int* order = (int*)(base + 262144 + 1048576);
  int* cnt = order + Nn;
  int* cur = cnt + 64;

  prep_kernel<<<(2 * Vv * G4 + 255) / 256, 256, 0, stream>>>(
      emb, Wih_f, Whh_f, bih_f, bhh_f, Wih_b, Whh_b, bih_b, bhh_b, BP, XGq, cnt);
  hist_kernel<<<Nn / 256, 256, 0, stream>>>(lens, cnt);
  prefix_kernel<<<1, 1, 0, stream>>>(cnt, cur);
  scatter_kernel<<<Nn / 256, 256, 0, stream>>>(lens, cur, order);
  bilstm_main<<<NTASK, NTHR, 0, stream>>>(cidx, lens, BP, XGq, order, out);
}

// Round 6
// 147.648 us; speedup vs baseline: 8.9429x; 1.5529x over previous
//
#include <hip/hip_runtime.h>
#include <math.h>

#define Vv 256
#define Ee 64
#define Hh 128
#define Nn 16384
#define Ll 24
#define G4 512      // 4*H
#define WB 32       // words per task
#define NTHR 512    // 8 waves
#define NGRP (Nn / WB)      // 512 groups
#define NTASK (NGRP * 2)    // 1024 tasks (group x dir) = grid

typedef _Float16 half8 __attribute__((ext_vector_type(8)));
typedef float f32x4 __attribute__((ext_vector_type(4)));

#define KS1 (-1.4426950408889634f)   // -log2(e): i,f,o rows -> 2^s = exp(-y)

// ---- fused prep + sort (blocks 0..1023: prep; block 1024: counting sort in LDS)
// XGq[d][c][u][bank] (f32): (emb[c]@Wih_d[j] + bih[j]+bhh[j]) * scale(bank), j=bank*128+u.
//   scale = KS1 for i,f,o banks (exp2-ready sigmoid args); g bank (2) kept RAW for Pade tanh.
// BP[d][kt][bank][g2][u][e] (f16): Whh_d[j][k]*scale(bank), k=kt*32+g2*8+e (B-frag order).
__global__ void prep_sort_kernel(const float* __restrict__ emb,
                                 const float* __restrict__ Wih_f, const float* __restrict__ Whh_f,
                                 const float* __restrict__ bih_f, const float* __restrict__ bhh_f,
                                 const float* __restrict__ Wih_b, const float* __restrict__ Whh_b,
                                 const float* __restrict__ bih_b, const float* __restrict__ bhh_b,
                                 const int* __restrict__ lens,
                                 _Float16* __restrict__ BP, float* __restrict__ XGq,
                                 int* __restrict__ order) {
  const int tid = threadIdx.x;
  if (blockIdx.x == 1024) {  // ---- sort block: hist + prefix + scatter, all in LDS
    __shared__ int hcnt[32];
    __shared__ int hcur[32];
    if (tid < 32) hcnt[tid] = 0;
    __syncthreads();
    for (int i = tid; i < Nn; i += 256) atomicAdd(&hcnt[lens[i]], 1);
    __syncthreads();
    if (tid == 0) {
      int s = 0;
      for (int b = 0; b <= Ll; b++) { hcur[b] = s; s += hcnt[b]; }
    }
    __syncthreads();
    for (int i = tid; i < Nn; i += 256) {
      int p = atomicAdd(&hcur[lens[i]], 1);
      order[p] = i;
    }
    return;
  }
  int i = blockIdx.x * 256 + tid;
  if (i < 2 * Vv * G4) {  // 262144
    int bank = i & 3, u = (i >> 2) & 127, c = (i >> 9) & 255, d = i >> 17;
    int j = bank * 128 + u;
    const float* Wih = d ? Wih_b : Wih_f;
    const float* bih = d ? bih_b : bih_f;
    const float* bhh = d ? bhh_b : bhh_f;
    float acc = bih[j] + bhh[j];
    const float4* e4 = (const float4*)(emb + c * Ee);
    const float4* w4 = (const float4*)(Wih + j * Ee);
#pragma unroll 4
    for (int k = 0; k < Ee / 4; k++) {
      float4 a = e4[k], b = w4[k];
      acc = fmaf(a.x, b.x, acc); acc = fmaf(a.y, b.y, acc);
      acc = fmaf(a.z, b.z, acc); acc = fmaf(a.w, b.w, acc);
    }
    XGq[i] = (bank == 2) ? acc : acc * KS1;
  }
  if (i < 2 * 4 * 4 * 4 * 128 * 8) {  // 131072
    int e = i & 7, u = (i >> 3) & 127, g2 = (i >> 10) & 3,
        bank = (i >> 12) & 3, kt = (i >> 14) & 3, d = (i >> 16) & 1;
    int j = bank * 128 + u;
    int k = kt * 32 + g2 * 8 + e;
    const float* Whh = d ? Whh_b : Whh_f;
    float w = Whh[j * Hh + k];
    BP[i] = (_Float16)((bank == 2) ? w : w * KS1);
  }
}

// Pade(5,4) tanh: tanh x ~= x(x^4+105x^2+945)/(15x^4+420x^2+945), num clamped to +-den
// (exact saturation for |x|>~3.98). Err <= 4e-4 for |x|<=3, <=3e-5 for |x|<=1.5.
#define PADE_TANH(X, NUM, DEN)                                                \
    float X##_2 = (X) * (X);                                                  \
    float NUM = (X) * fmaf(X##_2, fmaf(X##_2, 1.0f, 105.0f), 945.0f);         \
    float DEN = fmaf(X##_2, fmaf(X##_2, 15.0f, 420.0f), 945.0f);              \
    NUM = fminf(fmaxf(NUM, -DEN), DEN);

// Gates: A=exp(-yi), B=exp(-yf), E=exp(-yo) via exp2 of prescaled accs; g,tanh(c) via Pade.
// cn = c/(1+B) + g/(1+A) = (c*aA*gd + gn*aB) * rcp(aA*aB*gd)
// hn = tanh(cn)/(1+E)    = tn * rcp(td*aE)
// 5 trans/set (3 exp2 + 2 rcp), was 7.
#define GATES(ACC, CS, HR, MT, WLEN)                                          \
  _Pragma("unroll") for (int r = 0; r < 4; r++) {                             \
    float Av = __builtin_amdgcn_exp2f(ACC[0][r]);                             \
    float Bv = __builtin_amdgcn_exp2f(ACC[1][r]);                             \
    float yg = ACC[2][r];                                                     \
    float Ev = __builtin_amdgcn_exp2f(ACC[3][r]);                             \
    float aA = 1.0f + Av, aB = 1.0f + Bv, aE = 1.0f + Ev;                     \
    PADE_TANH(yg, gn, gd)                                                     \
    float R1 = __builtin_amdgcn_rcpf(aA * aB * gd);                           \
    float cn = fmaf(CS[r] * aA, gd, gn * aB) * R1;                            \
    PADE_TANH(cn, tn, td)                                                     \
    float R2 = __builtin_amdgcn_rcpf(td * aE);                                \
    float hn = tn * R2;                                                       \
    if (t < WLEN[r]) {                                                        \
      CS[r] = cn; HR[r] = hn;                                                 \
      hw[(MT)*16 + qg * 4 + r][u] = (_Float16)hn;                             \
    }                                                                         \
  }

#define LOADX(XV, P0, MT, TT)                                                 \
  _Pragma("unroll") for (int r = 0; r < 4; r++) {                             \
    int pos = P0[r] + sgn * (TT);                                             \
    pos = pos < 0 ? 0 : pos;                                                  \
    int c = idx_s[(MT)*16 + qg * 4 + r][pos];                                 \
    XV[r] = xq[(c << 7) + u];                                                 \
  }

// ---- main: 1024 tasks (32 sorted words x dir), one 8-wave block each, longest first.
// Whh in VGPRs (Bf). Per step: prefetched XGq float4 gather -> acc; ds_read h frags
// (double-buffered LDS, ONE barrier/step); MFMA; Pade/shared-rcp gates; f16 h writeback.
__global__ __launch_bounds__(NTHR, 2) void bilstm_main(
    const int* __restrict__ cidx, const int* __restrict__ lens,
    const _Float16* __restrict__ BP, const float* __restrict__ XGq,
    const int* __restrict__ order, float* __restrict__ out) {
  __shared__ __align__(16) _Float16 hs[2][WB][136];  // dbuf; pad 136 -> 2-way bank (free)
  __shared__ int idx_s[WB][Ll];
  __shared__ int wid_s[WB];
  __shared__ int len_s[WB];

  const int tid = threadIdx.x;
  const int lane = tid & 63;
  const int wv = tid >> 6;        // wave 0..7
  const int qg = lane >> 4;       // quarter-group 0..3
  const int li = lane & 15;       // col within tile
  const int u = (wv << 4) + li;   // this lane's unit 0..127

  const int task = NTASK - 1 - (int)blockIdx.x;  // longest first
  const int g = task >> 1;
  const int d = task & 1;
  const int sgn = d ? -1 : 1;

  if (tid < WB) { int w = order[g * WB + tid]; wid_s[tid] = w; len_s[tid] = lens[w]; }
  __syncthreads();
  for (int i = tid; i < WB * Ll; i += NTHR) {
    int w = i / Ll, p = i - w * Ll;
    idx_s[w][p] = cidx[(size_t)wid_s[w] * Ll + p];
  }
  for (int i = tid; i < 2 * WB * 136; i += NTHR) ((_Float16*)hs)[i] = (_Float16)0.0f;
  __syncthreads();

  const int maxlen = len_s[WB - 1];  // ascending sort -> group max

  // Whh fragments -> registers (pre-scaled), once per task.
  half8 Bf[4][4];
  {
    const _Float16* BPd = BP + (size_t)d * 65536;
#pragma unroll
    for (int kt = 0; kt < 4; kt++)
#pragma unroll
      for (int bank = 0; bank < 4; bank++)
        Bf[kt][bank] = *(const half8*)(BPd + (size_t)((((kt * 4 + bank) * 4 + qg) * 128 + u) << 3));
  }

  const f32x4* xq = (const f32x4*)(XGq + (size_t)d * (Vv * G4));

  int wlen0[4], wlen1[4], p0a[4], p0b[4];
#pragma unroll
  for (int r = 0; r < 4; r++) {
    wlen0[r] = len_s[qg * 4 + r];        // C/D row = (lane>>4)*4 + reg
    wlen1[r] = len_s[16 + qg * 4 + r];
    p0a[r] = d ? (wlen0[r] - 1) : 0;
    p0b[r] = d ? (wlen1[r] - 1) : 0;
  }
  float cst0[4], cst1[4], hreg0[4], hreg1[4];
#pragma unroll
  for (int r = 0; r < 4; r++) { cst0[r] = 0.0f; cst1[r] = 0.0f; hreg0[r] = 0.0f; hreg1[r] = 0.0f; }

  f32x4 x4a[4], x4b[4];
  if (maxlen > 0) { LOADX(x4a, p0a, 0, 0); LOADX(x4b, p0b, 1, 0); }

  for (int t = 0; t < maxlen; t++) {
    _Float16 (*hw)[136] = hs[t & 1];                 // write buffer
    const _Float16 (*hr)[136] = hs[(t ^ 1) & 1];     // read buffer = (t-1)&1

    // acc init from prefetched gather (loads issued last iteration)
    f32x4 acc0[4], acc1[4];
#pragma unroll
    for (int bank = 0; bank < 4; bank++)
#pragma unroll
      for (int r = 0; r < 4; r++) {
        acc0[bank][r] = x4a[r][bank];
        acc1[bank][r] = x4b[r][bank];
      }

    if (t > 0) {  // h==0 at t=0: matmul contributes nothing
      half8 a0[4], a1[4];
#pragma unroll
      for (int kt = 0; kt < 4; kt++) {
        a0[kt] = *(const half8*)&hr[li][kt * 32 + qg * 8];
        a1[kt] = *(const half8*)&hr[16 + li][kt * 32 + qg * 8];
      }
#pragma unroll
      for (int bank = 0; bank < 4; bank++) {
        f32x4 v0 = acc0[bank], v1 = acc1[bank];
#pragma unroll
        for (int kt = 0; kt < 4; kt++) {
          v0 = __builtin_amdgcn_mfma_f32_16x16x32_f16(a0[kt], Bf[kt][bank], v0, 0, 0, 0);
          v1 = __builtin_amdgcn_mfma_f32_16x16x32_f16(a1[kt], Bf[kt][bank], v1, 0, 0, 0);
        }
        acc0[bank] = v0; acc1[bank] = v1;
      }
    }

    // prefetch next step's gather; L2 latency hides under the trans-heavy gates.
    if (t + 1 < maxlen) { LOADX(x4a, p0a, 0, t + 1); LOADX(x4b, p0b, 1, t + 1); }

    GATES(acc0, cst0, hreg0, 0, wlen0);
    GATES(acc1, cst1, hreg1, 1, wlen1);

    __syncthreads();  // writes to hs[t&1] visible before next step reads it
  }

  // output from fp32 regs
#pragma unroll
  for (int r = 0; r < 4; r++) {
    out[(size_t)wid_s[qg * 4 + r] * (2 * Hh) + d * Hh + u] = hreg0[r];
    out[(size_t)wid_s[16 + qg * 4 + r] * (2 * Hh) + d * Hh + u] = hreg1[r];
  }
}

extern "C" void kernel_launch(void* const* d_in, const int* in_sizes, int n_in,
                              void* d_out, int out_size, void* d_ws, size_t ws_size,
                              hipStream_t stream) {
  const int* cidx = (const int*)d_in[0];
  const int* lens = (const int*)d_in[1];
  const float* emb = (const float*)d_in[2];
  const float* Wih_f = (const float*)d_in[3];
  const float* Whh_f = (const float*)d_in[4];
  const float* bih_f = (const float*)d_in[5];
  const float* bhh_f = (const float*)d_in[6];
  const float* Wih_b = (const float*)d_in[7];
  const float* Whh_b = (const float*)d_in[8];
  const float* bih_b = (const float*)d_in[9];
  const float* bhh_b = (const float*)d_in[10];
  float* out = (float*)d_out;

  // ws: BP f16 [131072] = 256KB | XGq f32 [2*256*512] = 1MB | order[N]
  char* base = (char*)d_ws;
  _Float16* BP = (_Float16*)base;
  float* XGq = (float*)(base + 262144);
  int* order = (int*)(base + 262144 + 1048576);

  prep_sort_kernel<<<1025, 256, 0, stream>>>(
      emb, Wih_f, Whh_f, bih_f, bhh_f, Wih_b, Whh_b, bih_b, bhh_b, lens, BP, XGq, order);
  bilstm_main<<<NTASK, NTHR, 0, stream>>>(cidx, lens, BP, XGq, order, out);
}